// Round 2
// baseline (315.278 us; speedup 1.0000x reference)
//
#include <hip/hip_runtime.h>
#include <hip/hip_bf16.h>
#include <stdint.h>

#define T_TOK 2048
#define DIM   1024
#define HDIM  2048
#define NE    8
#define ROWS_PAD 4224   // 4096 routed rows + 128 pad for tile overrun

typedef __attribute__((ext_vector_type(8))) short bf16x8;
typedef __attribute__((ext_vector_type(4))) float f32x4;

__device__ __forceinline__ unsigned short f2bf(float f) {
    union { float f; unsigned int u; } v; v.f = f;
    unsigned int r = v.u + 0x7FFF + ((v.u >> 16) & 1);   // round-nearest-even
    return (unsigned short)(r >> 16);
}

__device__ __forceinline__ void gload16(const void* g, void* l) {
    __builtin_amdgcn_global_load_lds(
        (const __attribute__((address_space(1))) void*)g,
        (__attribute__((address_space(3))) void*)l, 16, 0, 0);
}

// ---------------- transpose + fp32->bf16 convert: in[b][R][C] -> out[b][C][R]
__global__ void transpose_cvt(const float* __restrict__ in, unsigned short* __restrict__ out,
                              int R, int C) {
    __shared__ float tile[32][33];
    int b = blockIdx.z;
    int bx = blockIdx.x, by = blockIdx.y;
    int tx = threadIdx.x & 31, ty = threadIdx.x >> 5;
    const float* ip = in + (size_t)b * R * C;
    unsigned short* op = out + (size_t)b * R * C;
#pragma unroll
    for (int i = 0; i < 4; ++i) {
        int r = by * 32 + ty + i * 8;
        tile[ty + i * 8][tx] = ip[(size_t)r * C + bx * 32 + tx];
    }
    __syncthreads();
#pragma unroll
    for (int i = 0; i < 4; ++i) {
        int oc = bx * 32 + ty + i * 8;   // row of out (= col of in)
        int orw = by * 32 + tx;          // col of out (= row of in)
        op[(size_t)oc * R + orw] = f2bf(tile[tx][ty + i * 8]);
    }
}

// ---------------- router: logits = x @ rw, top-2 softmax, counts
__global__ void router_kernel(const float* __restrict__ x, const float* __restrict__ rw,
                              int* __restrict__ counts, int* __restrict__ top_idx,
                              float* __restrict__ top_w) {
    int wid = (blockIdx.x * blockDim.x + threadIdx.x) >> 6;
    int lane = threadIdx.x & 63;
    if (wid >= T_TOK) return;
    float acc[NE];
#pragma unroll
    for (int e = 0; e < NE; ++e) acc[e] = 0.f;
    const float* xr = x + (size_t)wid * DIM;
    for (int i = lane; i < DIM; i += 64) {
        float xv = xr[i];
        const float* wr = rw + (size_t)i * NE;
#pragma unroll
        for (int e = 0; e < NE; ++e) acc[e] += xv * wr[e];
    }
#pragma unroll
    for (int off = 32; off; off >>= 1) {
#pragma unroll
        for (int e = 0; e < NE; ++e) acc[e] += __shfl_xor(acc[e], off, 64);
    }
    if (lane == 0) {
        float v0 = -1e30f, v1 = -1e30f; int i0 = 0, i1 = 0;
#pragma unroll
        for (int e = 0; e < NE; ++e) {
            float v = acc[e];
            if (v > v0) { v1 = v0; i1 = i0; v0 = v; i0 = e; }
            else if (v > v1) { v1 = v; i1 = e; }
        }
        float e1 = __expf(v1 - v0);
        float s = 1.f + e1;
        top_idx[wid * 2]     = i0;
        top_idx[wid * 2 + 1] = i1;
        top_w[wid * 2]     = 1.f / s;
        top_w[wid * 2 + 1] = e1 / s;
        atomicAdd(&counts[i0], 1);
        atomicAdd(&counts[i1], 1);
    }
}

// ---------------- tiny exclusive scan of 8 counts
__global__ void scan_kernel(const int* __restrict__ counts, int* __restrict__ offsets,
                            int* __restrict__ cursors) {
    if (threadIdx.x == 0) {
        int run = 0;
        for (int e = 0; e < NE; ++e) { offsets[e] = run; cursors[e] = run; run += counts[e]; }
    }
}

// ---------------- gather: pack each token's row (bf16) into its 2 experts' segments
__global__ void gather_kernel(const float* __restrict__ x, const int* __restrict__ top_idx,
                              const float* __restrict__ top_w, int* __restrict__ cursors,
                              int* __restrict__ row_tok, float* __restrict__ row_w,
                              unsigned short* __restrict__ Abuf) {
    int t = blockIdx.x;
    __shared__ int pos[2];
    if (threadIdx.x < 2) {
        int k = threadIdx.x;
        int e = top_idx[t * 2 + k];
        int p = atomicAdd(&cursors[e], 1);
        pos[k] = p;
        row_tok[p] = t;
        row_w[p] = top_w[t * 2 + k];
    }
    __syncthreads();
    const float4* xr = (const float4*)(x + (size_t)t * DIM);
    float4 v = xr[threadIdx.x];
    ushort4 b;
    b.x = f2bf(v.x); b.y = f2bf(v.y); b.z = f2bf(v.z); b.w = f2bf(v.w);
    ushort4* A4 = (ushort4*)Abuf;
    A4[(size_t)pos[0] * (DIM / 4) + threadIdx.x] = b;
    A4[(size_t)pos[1] * (DIM / 4) + threadIdx.x] = b;
}

// ---------------- GEMM1: hidden = silu(A @ WgT^T) * (A @ WuT^T), per expert
// A: Abuf rows (bf16, stride DIM); B: WgT/WuT [e][H][D] (k=D contiguous)
__global__ __launch_bounds__(256, 2)
void gemm1_kernel(const unsigned short* __restrict__ Abuf,
                  const unsigned short* __restrict__ WgT,
                  const unsigned short* __restrict__ WuT,
                  unsigned short* __restrict__ Hbuf,
                  const int* __restrict__ offsets, const int* __restrict__ counts) {
    const int e = blockIdx.z;
    const int cnt = counts[e];
    const int mtile = blockIdx.y;
    if (mtile * 128 >= cnt) return;
    const int n0 = blockIdx.x * 128;
    const int row0 = offsets[e] + mtile * 128;

    __shared__ unsigned short As[128 * 32];
    __shared__ unsigned short Bg[128 * 32];
    __shared__ unsigned short Bu[128 * 32];

    const int tid = threadIdx.x;
    const int wave = tid >> 6, lane = tid & 63;
    const int wm = wave >> 1, wn = wave & 1;

    f32x4 accg[4][4], accu[4][4];
#pragma unroll
    for (int i = 0; i < 4; ++i)
#pragma unroll
        for (int j = 0; j < 4; ++j) {
            accg[i][j] = (f32x4){0.f, 0.f, 0.f, 0.f};
            accu[i][j] = (f32x4){0.f, 0.f, 0.f, 0.f};
        }

    const int rseg = lane >> 2;          // 0..15 rows within 16-row segment
    const int koff = (lane & 3) * 8;     // 0,8,16,24 within BK=32
    const unsigned short* Ag0 = Abuf + (size_t)(row0 + wave * 32) * DIM;
    const unsigned short* Bgg = WgT + (size_t)e * HDIM * DIM + (size_t)(n0 + wave * 32) * DIM;
    const unsigned short* Bug = WuT + (size_t)e * HDIM * DIM + (size_t)(n0 + wave * 32) * DIM;
    unsigned short* Asl = &As[wave * 32 * 32];
    unsigned short* Bgl = &Bg[wave * 32 * 32];
    unsigned short* Bul = &Bu[wave * 32 * 32];

    for (int kt = 0; kt < DIM; kt += 32) {
        __syncthreads();
#pragma unroll
        for (int j = 0; j < 2; ++j) {
            int r = j * 16 + rseg;
            gload16(Ag0 + (size_t)r * DIM + kt + koff, Asl + (j * 16) * 32);
            gload16(Bgg + (size_t)r * DIM + kt + koff, Bgl + (j * 16) * 32);
            gload16(Bug + (size_t)r * DIM + kt + koff, Bul + (j * 16) * 32);
        }
        __syncthreads();
        const int krd = (lane >> 4) * 8;
        const int rsel = lane & 15;
        bf16x8 af[4], bg[4], bu[4];
#pragma unroll
        for (int i = 0; i < 4; ++i) {
            af[i] = *(const bf16x8*)&As[(wm * 64 + i * 16 + rsel) * 32 + krd];
            bg[i] = *(const bf16x8*)&Bg[(wn * 64 + i * 16 + rsel) * 32 + krd];
            bu[i] = *(const bf16x8*)&Bu[(wn * 64 + i * 16 + rsel) * 32 + krd];
        }
#pragma unroll
        for (int i = 0; i < 4; ++i)
#pragma unroll
            for (int j = 0; j < 4; ++j) {
                accg[i][j] = __builtin_amdgcn_mfma_f32_16x16x32_bf16(af[i], bg[j], accg[i][j], 0, 0, 0);
                accu[i][j] = __builtin_amdgcn_mfma_f32_16x16x32_bf16(af[i], bu[j], accu[i][j], 0, 0, 0);
            }
    }

    const int c = lane & 15, rbase = (lane >> 4) * 4;
    const int obase = offsets[e];
#pragma unroll
    for (int i = 0; i < 4; ++i) {
#pragma unroll
        for (int r = 0; r < 4; ++r) {
            int lrow = mtile * 128 + wm * 64 + i * 16 + rbase + r;
            if (lrow < cnt) {
                size_t orow = (size_t)(obase + lrow);
#pragma unroll
                for (int j = 0; j < 4; ++j) {
                    float g = accg[i][j][r], u = accu[i][j][r];
                    float h = g * u / (1.f + __expf(-g));
                    Hbuf[orow * HDIM + n0 + wn * 64 + j * 16 + c] = f2bf(h);
                }
            }
        }
    }
}

// ---------------- GEMM2: y[tok] += w * (hidden @ WdT^T)
// A: Hbuf rows (stride HDIM); B: WdT [e][D][H] (k=H contiguous)
__global__ __launch_bounds__(256, 2)
void gemm2_kernel(const unsigned short* __restrict__ Hbuf,
                  const unsigned short* __restrict__ WdT,
                  float* __restrict__ y,
                  const int* __restrict__ offsets, const int* __restrict__ counts,
                  const int* __restrict__ row_tok, const float* __restrict__ row_w) {
    const int e = blockIdx.z;
    const int cnt = counts[e];
    const int mtile = blockIdx.y;
    if (mtile * 128 >= cnt) return;
    const int n0 = blockIdx.x * 128;
    const int row0 = offsets[e] + mtile * 128;

    __shared__ unsigned short As[128 * 32];
    __shared__ unsigned short Bs[128 * 32];

    const int tid = threadIdx.x;
    const int wave = tid >> 6, lane = tid & 63;
    const int wm = wave >> 1, wn = wave & 1;

    f32x4 acc[4][4];
#pragma unroll
    for (int i = 0; i < 4; ++i)
#pragma unroll
        for (int j = 0; j < 4; ++j) acc[i][j] = (f32x4){0.f, 0.f, 0.f, 0.f};

    const int rseg = lane >> 2;
    const int koff = (lane & 3) * 8;
    const unsigned short* Ag0 = Hbuf + (size_t)(row0 + wave * 32) * HDIM;
    const unsigned short* Bgg = WdT + (size_t)e * DIM * HDIM + (size_t)(n0 + wave * 32) * HDIM;
    unsigned short* Asl = &As[wave * 32 * 32];
    unsigned short* Bsl = &Bs[wave * 32 * 32];

    for (int kt = 0; kt < HDIM; kt += 32) {
        __syncthreads();
#pragma unroll
        for (int j = 0; j < 2; ++j) {
            int r = j * 16 + rseg;
            gload16(Ag0 + (size_t)r * HDIM + kt + koff, Asl + (j * 16) * 32);
            gload16(Bgg + (size_t)r * HDIM + kt + koff, Bsl + (j * 16) * 32);
        }
        __syncthreads();
        const int krd = (lane >> 4) * 8;
        const int rsel = lane & 15;
        bf16x8 af[4], bf[4];
#pragma unroll
        for (int i = 0; i < 4; ++i) {
            af[i] = *(const bf16x8*)&As[(wm * 64 + i * 16 + rsel) * 32 + krd];
            bf[i] = *(const bf16x8*)&Bs[(wn * 64 + i * 16 + rsel) * 32 + krd];
        }
#pragma unroll
        for (int i = 0; i < 4; ++i)
#pragma unroll
            for (int j = 0; j < 4; ++j)
                acc[i][j] = __builtin_amdgcn_mfma_f32_16x16x32_bf16(af[i], bf[j], acc[i][j], 0, 0, 0);
    }

    const int c = lane & 15, rbase = (lane >> 4) * 4;
    const int obase = offsets[e];
#pragma unroll
    for (int i = 0; i < 4; ++i) {
#pragma unroll
        for (int r = 0; r < 4; ++r) {
            int lrow = mtile * 128 + wm * 64 + i * 16 + rbase + r;
            if (lrow < cnt) {
                int grow = obase + lrow;
                int tok = row_tok[grow];
                float w = row_w[grow];
#pragma unroll
                for (int j = 0; j < 4; ++j) {
                    atomicAdd(&y[(size_t)tok * DIM + n0 + wn * 64 + j * 16 + c], w * acc[i][j][r]);
                }
            }
        }
    }
}

extern "C" void kernel_launch(void* const* d_in, const int* in_sizes, int n_in,
                              void* d_out, int out_size, void* d_ws, size_t ws_size,
                              hipStream_t stream) {
    const float* x  = (const float*)d_in[0];
    const float* rw = (const float*)d_in[1];
    const float* gw = (const float*)d_in[2];
    const float* uw = (const float*)d_in[3];
    const float* dw = (const float*)d_in[4];
    float* y = (float*)d_out;

    char* ws = (char*)d_ws;
    int*   counts  = (int*)(ws + 0);
    int*   cursors = (int*)(ws + 32);
    int*   offsets = (int*)(ws + 64);
    int*   top_idx = (int*)(ws + 128);
    float* top_w   = (float*)(ws + 128 + 16384);
    int*   row_tok = (int*)(ws + 128 + 32768);
    float* row_w   = (float*)(ws + 128 + 32768 + 16896);
    size_t off = 128 + 32768 + 2 * 16896;
    off = (off + 255) & ~(size_t)255;
    unsigned short* Abuf = (unsigned short*)(ws + off); off += (size_t)ROWS_PAD * DIM * 2;
    unsigned short* Hbuf = (unsigned short*)(ws + off); off += (size_t)ROWS_PAD * HDIM * 2;
    unsigned short* WgT  = (unsigned short*)(ws + off); off += (size_t)NE * DIM * HDIM * 2;
    unsigned short* WuT  = (unsigned short*)(ws + off); off += (size_t)NE * DIM * HDIM * 2;
    unsigned short* WdT  = (unsigned short*)(ws + off); off += (size_t)NE * DIM * HDIM * 2;
    if (ws_size < off) return;  // workspace too small: fail loudly (zero output)

    hipMemsetAsync(counts, 0, 32, stream);
    hipMemsetAsync(d_out, 0, (size_t)out_size * 4, stream);

    // weight transpose+convert (independent of routing)
    transpose_cvt<<<dim3(HDIM / 32, DIM / 32, NE), 256, 0, stream>>>(gw, WgT, DIM, HDIM);
    transpose_cvt<<<dim3(HDIM / 32, DIM / 32, NE), 256, 0, stream>>>(uw, WuT, DIM, HDIM);
    transpose_cvt<<<dim3(DIM / 32, HDIM / 32, NE), 256, 0, stream>>>(dw, WdT, HDIM, DIM);

    router_kernel<<<T_TOK / 4, 256, 0, stream>>>(x, rw, counts, top_idx, top_w);
    scan_kernel<<<1, 64, 0, stream>>>(counts, offsets, cursors);
    gather_kernel<<<T_TOK, 256, 0, stream>>>(x, top_idx, top_w, cursors, row_tok, row_w, Abuf);

    gemm1_kernel<<<dim3(HDIM / 128, 16, NE), 256, 0, stream>>>(Abuf, WgT, WuT, Hbuf, offsets, counts);
    gemm2_kernel<<<dim3(DIM / 128, 16, NE), 256, 0, stream>>>(Hbuf, WdT, y, offsets, counts, row_tok, row_w);
}

// Round 5
// 281.921 us; speedup vs baseline: 1.1183x; 1.1183x over previous
//
#include <hip/hip_runtime.h>
#include <hip/hip_bf16.h>
#include <stdint.h>

#define T_TOK 2048
#define DIM   1024
#define HDIM  2048
#define NE    8
#define ROWS_PAD 4224   // 4096 routed rows + 128 pad for tile overrun

typedef __attribute__((ext_vector_type(8))) short bf16x8;
typedef __attribute__((ext_vector_type(4))) float f32x4;

__device__ __forceinline__ unsigned short f2bf(float f) {
    union { float f; unsigned int u; } v; v.f = f;
    unsigned int r = v.u + 0x7FFF + ((v.u >> 16) & 1);   // round-nearest-even
    return (unsigned short)(r >> 16);
}

__device__ __forceinline__ void gload16(const void* g, void* l) {
    __builtin_amdgcn_global_load_lds(
        (const __attribute__((address_space(1))) void*)g,
        (__attribute__((address_space(3))) void*)l, 16, 0, 0);
}

// ---------------- transpose + fp32->bf16 convert: in[b][R][C] -> out[b][C][R]
__global__ void transpose_cvt(const float* __restrict__ in, unsigned short* __restrict__ out,
                              int R, int C) {
    __shared__ float tile[32][33];
    int b = blockIdx.z;
    int bx = blockIdx.x, by = blockIdx.y;
    int tx = threadIdx.x & 31, ty = threadIdx.x >> 5;
    const float* ip = in + (size_t)b * R * C;
    unsigned short* op = out + (size_t)b * R * C;
#pragma unroll
    for (int i = 0; i < 4; ++i) {
        int r = by * 32 + ty + i * 8;
        tile[ty + i * 8][tx] = ip[(size_t)r * C + bx * 32 + tx];
    }
    __syncthreads();
#pragma unroll
    for (int i = 0; i < 4; ++i) {
        int oc = bx * 32 + ty + i * 8;   // row of out (= col of in)
        int orw = by * 32 + tx;          // col of out (= row of in)
        op[(size_t)oc * R + orw] = f2bf(tile[tx][ty + i * 8]);
    }
}

// ---------------- router: logits = x @ rw, top-2 softmax, counts
__global__ void router_kernel(const float* __restrict__ x, const float* __restrict__ rw,
                              int* __restrict__ counts, int* __restrict__ top_idx,
                              float* __restrict__ top_w) {
    int wid = (blockIdx.x * blockDim.x + threadIdx.x) >> 6;
    int lane = threadIdx.x & 63;
    if (wid >= T_TOK) return;
    float acc[NE];
#pragma unroll
    for (int e = 0; e < NE; ++e) acc[e] = 0.f;
    const float* xr = x + (size_t)wid * DIM;
    for (int i = lane; i < DIM; i += 64) {
        float xv = xr[i];
        const float* wr = rw + (size_t)i * NE;
#pragma unroll
        for (int e = 0; e < NE; ++e) acc[e] += xv * wr[e];
    }
#pragma unroll
    for (int off = 32; off; off >>= 1) {
#pragma unroll
        for (int e = 0; e < NE; ++e) acc[e] += __shfl_xor(acc[e], off, 64);
    }
    if (lane == 0) {
        float v0 = -1e30f, v1 = -1e30f; int i0 = 0, i1 = 0;
#pragma unroll
        for (int e = 0; e < NE; ++e) {
            float v = acc[e];
            if (v > v0) { v1 = v0; i1 = i0; v0 = v; i0 = e; }
            else if (v > v1) { v1 = v; i1 = e; }
        }
        float e1 = __expf(v1 - v0);
        float s = 1.f + e1;
        top_idx[wid * 2]     = i0;
        top_idx[wid * 2 + 1] = i1;
        top_w[wid * 2]     = 1.f / s;
        top_w[wid * 2 + 1] = e1 / s;
        atomicAdd(&counts[i0], 1);
        atomicAdd(&counts[i1], 1);
    }
}

// ---------------- tiny exclusive scan of 8 counts
__global__ void scan_kernel(const int* __restrict__ counts, int* __restrict__ offsets,
                            int* __restrict__ cursors) {
    if (threadIdx.x == 0) {
        int run = 0;
        for (int e = 0; e < NE; ++e) { offsets[e] = run; cursors[e] = run; run += counts[e]; }
    }
}

// ---------------- gather: pack each token's row (bf16) into its 2 experts' segments
__global__ void gather_kernel(const float* __restrict__ x, const int* __restrict__ top_idx,
                              const float* __restrict__ top_w, int* __restrict__ cursors,
                              int* __restrict__ row_tok, float* __restrict__ row_w,
                              unsigned short* __restrict__ Abuf) {
    int t = blockIdx.x;
    __shared__ int pos[2];
    if (threadIdx.x < 2) {
        int k = threadIdx.x;
        int e = top_idx[t * 2 + k];
        int p = atomicAdd(&cursors[e], 1);
        pos[k] = p;
        row_tok[p] = t;
        row_w[p] = top_w[t * 2 + k];
    }
    __syncthreads();
    const float4* xr = (const float4*)(x + (size_t)t * DIM);
    float4 v = xr[threadIdx.x];
    ushort4 b;
    b.x = f2bf(v.x); b.y = f2bf(v.y); b.z = f2bf(v.z); b.w = f2bf(v.w);
    ushort4* A4 = (ushort4*)Abuf;
    A4[(size_t)pos[0] * (DIM / 4) + threadIdx.x] = b;
    A4[(size_t)pos[1] * (DIM / 4) + threadIdx.x] = b;
}

// ---------------- GEMM1: hidden = silu(A @ WgT^T) * (A @ WuT^T), per expert
// 2-phase double-buffered, BK=32, XOR-swizzled LDS (c ^= (row>>1)&3).
__global__ __launch_bounds__(256, 2)
void gemm1_kernel(const unsigned short* __restrict__ Abuf,
                  const unsigned short* __restrict__ WgT,
                  const unsigned short* __restrict__ WuT,
                  unsigned short* __restrict__ Hbuf,
                  const int* __restrict__ offsets, const int* __restrict__ counts) {
    const int e = blockIdx.z;
    const int cnt = counts[e];
    const int mtile = blockIdx.y;
    if (mtile * 128 >= cnt) return;
    const int n0 = blockIdx.x * 128;
    const int row0 = offsets[e] + mtile * 128;

    __shared__ unsigned short As[2][128 * 32];
    __shared__ unsigned short Bg[2][128 * 32];
    __shared__ unsigned short Bu[2][128 * 32];

    const int tid = threadIdx.x;
    const int lane = tid & 63;
    const int wave = tid >> 6;
    const int wm = wave >> 1, wn = wave & 1;

    f32x4 accg[4][4], accu[4][4];
#pragma unroll
    for (int i = 0; i < 4; ++i)
#pragma unroll
        for (int j = 0; j < 4; ++j) {
            accg[i][j] = (f32x4){0.f, 0.f, 0.f, 0.f};
            accu[i][j] = (f32x4){0.f, 0.f, 0.f, 0.f};
        }

    // staging: 2 issues x 256 threads x 16B = 8 KB per array per K-step
    const int srow0 = tid >> 2;         // row within 64-row half (+i*64)
    const int sc0 = tid & 3;            // LDS 16B-chunk within 64B row
    const unsigned short* Aab = Abuf + (size_t)row0 * DIM;
    const unsigned short* Bgb = WgT + (size_t)e * HDIM * DIM + (size_t)n0 * DIM;
    const unsigned short* Bub = WuT + (size_t)e * HDIM * DIM + (size_t)n0 * DIM;

    auto stage = [&](int buf, int kt) {
#pragma unroll
        for (int i = 0; i < 2; ++i) {
            int row = i * 64 + srow0;
            int csrc = sc0 ^ ((row >> 1) & 3);            // inverse swizzle on source
            size_t go = (size_t)row * DIM + kt + csrc * 8;
            int lo = (i * 256 + tid) * 8;                 // linear LDS dest (shorts)
            gload16(Aab + go, &As[buf][lo]);
            gload16(Bgb + go, &Bg[buf][lo]);
            gload16(Bub + go, &Bu[buf][lo]);
        }
    };

    const int rsel = lane & 15;
    const int csrcf = lane >> 4;        // fragment k-chunk (0..3)

    stage(0, 0);
    int cur = 0;
    for (int kt = 0; kt < DIM; kt += 32) {
        __syncthreads();                 // buf[cur] staged (vmcnt drain had full prior step to overlap)
        if (kt + 32 < DIM) stage(cur ^ 1, kt + 32);
        const unsigned short* Ac = As[cur];
        const unsigned short* Bgc = Bg[cur];
        const unsigned short* Buc = Bu[cur];
        bf16x8 af[4], bg[4], bu[4];
#pragma unroll
        for (int i = 0; i < 4; ++i) {
            int ra = wm * 64 + i * 16 + rsel;
            af[i] = *(const bf16x8*)&Ac[ra * 32 + (csrcf ^ ((ra >> 1) & 3)) * 8];
            int rb = wn * 64 + i * 16 + rsel;
            int cb = (csrcf ^ ((rb >> 1) & 3)) * 8;
            bg[i] = *(const bf16x8*)&Bgc[rb * 32 + cb];
            bu[i] = *(const bf16x8*)&Buc[rb * 32 + cb];
        }
#pragma unroll
        for (int i = 0; i < 4; ++i)
#pragma unroll
            for (int j = 0; j < 4; ++j) {
                accg[i][j] = __builtin_amdgcn_mfma_f32_16x16x32_bf16(af[i], bg[j], accg[i][j], 0, 0, 0);
                accu[i][j] = __builtin_amdgcn_mfma_f32_16x16x32_bf16(af[i], bu[j], accu[i][j], 0, 0, 0);
            }
        cur ^= 1;
    }

    const int c = lane & 15, rbase = (lane >> 4) * 4;
    const int obase = offsets[e];
#pragma unroll
    for (int i = 0; i < 4; ++i) {
#pragma unroll
        for (int r = 0; r < 4; ++r) {
            int lrow = mtile * 128 + wm * 64 + i * 16 + rbase + r;
            if (lrow < cnt) {
                size_t orow = (size_t)(obase + lrow);
#pragma unroll
                for (int j = 0; j < 4; ++j) {
                    float g = accg[i][j][r], u = accu[i][j][r];
                    float h = g * u / (1.f + __expf(-g));
                    Hbuf[orow * HDIM + n0 + wn * 64 + j * 16 + c] = f2bf(h);
                }
            }
        }
    }
}

// ---------------- GEMM2: y[tok] += w * (hidden @ WdT^T)
// 2-phase double-buffered, BK=64, XOR-swizzled LDS (c ^= row&7), K split x2.
__global__ __launch_bounds__(256, 2)
void gemm2_kernel(const unsigned short* __restrict__ Hbuf,
                  const unsigned short* __restrict__ WdT,
                  float* __restrict__ y,
                  const int* __restrict__ offsets, const int* __restrict__ counts,
                  const int* __restrict__ row_tok, const float* __restrict__ row_w) {
    const int e = blockIdx.z >> 1;
    const int kc = blockIdx.z & 1;
    const int cnt = counts[e];
    const int mtile = blockIdx.y;
    if (mtile * 128 >= cnt) return;
    const int n0 = blockIdx.x * 128;
    const int row0 = offsets[e] + mtile * 128;

    __shared__ unsigned short As[2][128 * 64];
    __shared__ unsigned short Bs[2][128 * 64];

    const int tid = threadIdx.x;
    const int lane = tid & 63;
    const int wave = tid >> 6;
    const int wm = wave >> 1, wn = wave & 1;

    f32x4 acc[4][4];
#pragma unroll
    for (int i = 0; i < 4; ++i)
#pragma unroll
        for (int j = 0; j < 4; ++j) acc[i][j] = (f32x4){0.f, 0.f, 0.f, 0.f};

    // staging: 4 issues x 256 threads x 16B = 16 KB per array per K-step
    const int srow0 = tid >> 3;          // row within 32-row quarter (+i*32)
    const int sc0 = tid & 7;             // LDS 16B-chunk within 128B row
    const unsigned short* Aab = Hbuf + (size_t)row0 * HDIM;
    const unsigned short* Bbb = WdT + (size_t)e * DIM * HDIM + (size_t)n0 * HDIM;

    auto stage = [&](int buf, int kt) {
#pragma unroll
        for (int i = 0; i < 4; ++i) {
            int row = i * 32 + srow0;
            int csrc = sc0 ^ (row & 7);                   // inverse swizzle on source
            size_t go = (size_t)row * HDIM + kt + csrc * 8;
            int lo = (i * 256 + tid) * 8;
            gload16(Aab + go, &As[buf][lo]);
            gload16(Bbb + go, &Bs[buf][lo]);
        }
    };

    const int rsel = lane & 15;
    const int csrcf = lane >> 4;

    const int kbeg = kc * (HDIM / 2);
    const int kend = kbeg + (HDIM / 2);

    stage(0, kbeg);
    int cur = 0;
    for (int kt = kbeg; kt < kend; kt += 64) {
        __syncthreads();
        if (kt + 64 < kend) stage(cur ^ 1, kt + 64);
        const unsigned short* Ac = As[cur];
        const unsigned short* Bc = Bs[cur];
#pragma unroll
        for (int kk = 0; kk < 2; ++kk) {
            bf16x8 af[4], bf[4];
#pragma unroll
            for (int i = 0; i < 4; ++i) {
                int ra = wm * 64 + i * 16 + rsel;
                af[i] = *(const bf16x8*)&Ac[ra * 64 + ((kk * 4 + csrcf) ^ (ra & 7)) * 8];
                int rb = wn * 64 + i * 16 + rsel;
                bf[i] = *(const bf16x8*)&Bc[rb * 64 + ((kk * 4 + csrcf) ^ (rb & 7)) * 8];
            }
#pragma unroll
            for (int i = 0; i < 4; ++i)
#pragma unroll
                for (int j = 0; j < 4; ++j)
                    acc[i][j] = __builtin_amdgcn_mfma_f32_16x16x32_bf16(af[i], bf[j], acc[i][j], 0, 0, 0);
        }
        cur ^= 1;
    }

    const int c = lane & 15, rbase = (lane >> 4) * 4;
    const int obase = offsets[e];
#pragma unroll
    for (int i = 0; i < 4; ++i) {
#pragma unroll
        for (int r = 0; r < 4; ++r) {
            int lrow = mtile * 128 + wm * 64 + i * 16 + rbase + r;
            if (lrow < cnt) {
                int grow = obase + lrow;
                int tok = row_tok[grow];
                float w = row_w[grow];
#pragma unroll
                for (int j = 0; j < 4; ++j) {
                    atomicAdd(&y[(size_t)tok * DIM + n0 + wn * 64 + j * 16 + c], w * acc[i][j][r]);
                }
            }
        }
    }
}

extern "C" void kernel_launch(void* const* d_in, const int* in_sizes, int n_in,
                              void* d_out, int out_size, void* d_ws, size_t ws_size,
                              hipStream_t stream) {
    const float* x  = (const float*)d_in[0];
    const float* rw = (const float*)d_in[1];
    const float* gw = (const float*)d_in[2];
    const float* uw = (const float*)d_in[3];
    const float* dw = (const float*)d_in[4];
    float* y = (float*)d_out;

    char* ws = (char*)d_ws;
    int*   counts  = (int*)(ws + 0);
    int*   cursors = (int*)(ws + 32);
    int*   offsets = (int*)(ws + 64);
    int*   top_idx = (int*)(ws + 128);
    float* top_w   = (float*)(ws + 128 + 16384);
    int*   row_tok = (int*)(ws + 128 + 32768);
    float* row_w   = (float*)(ws + 128 + 32768 + 16896);
    size_t off = 128 + 32768 + 2 * 16896;
    off = (off + 255) & ~(size_t)255;
    unsigned short* Abuf = (unsigned short*)(ws + off); off += (size_t)ROWS_PAD * DIM * 2;
    unsigned short* Hbuf = (unsigned short*)(ws + off); off += (size_t)ROWS_PAD * HDIM * 2;
    unsigned short* WgT  = (unsigned short*)(ws + off); off += (size_t)NE * DIM * HDIM * 2;
    unsigned short* WuT  = (unsigned short*)(ws + off); off += (size_t)NE * DIM * HDIM * 2;
    unsigned short* WdT  = (unsigned short*)(ws + off); off += (size_t)NE * DIM * HDIM * 2;
    if (ws_size < off) return;  // workspace too small: fail loudly (zero output)

    hipMemsetAsync(counts, 0, 32, stream);
    hipMemsetAsync(d_out, 0, (size_t)out_size * 4, stream);

    // weight transpose+convert (independent of routing)
    transpose_cvt<<<dim3(HDIM / 32, DIM / 32, NE), 256, 0, stream>>>(gw, WgT, DIM, HDIM);
    transpose_cvt<<<dim3(HDIM / 32, DIM / 32, NE), 256, 0, stream>>>(uw, WuT, DIM, HDIM);
    transpose_cvt<<<dim3(DIM / 32, HDIM / 32, NE), 256, 0, stream>>>(dw, WdT, HDIM, DIM);

    router_kernel<<<T_TOK / 4, 256, 0, stream>>>(x, rw, counts, top_idx, top_w);
    scan_kernel<<<1, 64, 0, stream>>>(counts, offsets, cursors);
    gather_kernel<<<T_TOK, 256, 0, stream>>>(x, top_idx, top_w, cursors, row_tok, row_w, Abuf);

    gemm1_kernel<<<dim3(HDIM / 128, 16, NE), 256, 0, stream>>>(Abuf, WgT, WuT, Hbuf, offsets, counts);
    gemm2_kernel<<<dim3(DIM / 128, 16, NE * 2), 256, 0, stream>>>(Hbuf, WdT, y, offsets, counts, row_tok, row_w);
}